// Round 7
// baseline (318.066 us; speedup 1.0000x reference)
//
#include <hip/hip_runtime.h>

// ---------------------------------------------------------------------------
// HTGT layer: sort-by-type + bf16 MFMA pipeline
// R7: k_qkv persistent weight-resident blocks — grid=256 (1/CU), dynamic LDS
//     159744B holds Wq+Wk+Wv (padded) for the block's etype + single A-tile
//     buffer; each block loops ~6 contiguous 64-row tiles, re-staging weights
//     only on etype change. 2 barriers/tile, q/k/v GEMMs back-to-back.
//     (R6: every block staged 113KB weights for 0.5us of MFMA -> Mfma 5.8%.)
//     k_prep: one wave per (edge, s|d) half -> serial chain halved.
//     k_convw: LDS-tiled 32x32 transpose (was uncoalesced 2B scatter).
// ---------------------------------------------------------------------------

typedef __attribute__((ext_vector_type(8))) short short8;
typedef __attribute__((ext_vector_type(4))) float f32x4;

__device__ __forceinline__ unsigned short f2bf(float f){
  union { float f; unsigned u; } x; x.f = f;
  unsigned r = x.u + 0x7FFFu + ((x.u >> 16) & 1u);
  return (unsigned short)(r >> 16);
}
__device__ __forceinline__ float bf2f(unsigned short b){
  union { unsigned u; float f; } x; x.u = ((unsigned)b) << 16;
  return x.f;
}

// ---------------- setup kernels ----------------

__global__ void k_zero(int* __restrict__ p, int n){
  int i = blockIdx.x*256 + threadIdx.x;
  if(i < n) p[i] = 0;
}

__global__ __launch_bounds__(256) void k_hist(
    const int* __restrict__ etype, const int* __restrict__ dst_idx,
    const int* __restrict__ ntype,
    int* cnt_e, int* cnt_d, int* cnt_n, int E, int M){
  __shared__ int le[8], ln[4];
  int tid = threadIdx.x;
  if(tid < 8) le[tid] = 0;
  if(tid < 4) ln[tid] = 0;
  __syncthreads();
  int g = blockIdx.x*256 + tid;
  if(g < E){ atomicAdd(&le[etype[g]], 1); atomicAdd(&cnt_d[dst_idx[g]], 1); }
  if(g < M){ atomicAdd(&ln[ntype[g]], 1); }
  __syncthreads();
  if(tid < 8 && le[tid]) atomicAdd(&cnt_e[tid], le[tid]);
  if(tid < 4 && ln[tid]) atomicAdd(&cnt_n[tid], ln[tid]);
}

__global__ __launch_bounds__(1024) void k_scan(const int* __restrict__ cnt_e, int* off_e,
                                               const int* __restrict__ cnt_n, int* off_n,
                                               const int* __restrict__ cnt_d, int* off_d, int M){
  __shared__ int part[1024];
  int tid = threadIdx.x;
  if(tid == 0){
    int s = 0;
    for(int i=0;i<8;i++){ off_e[i]=s; s+=cnt_e[i]; } off_e[8]=s;
    s = 0;
    for(int i=0;i<4;i++){ off_n[i]=s; s+=cnt_n[i]; } off_n[4]=s;
  }
  int per = (M + 1023) >> 10;
  int s = 0;
  for(int j=0;j<per;j++){ int idx = tid*per + j; if(idx < M) s += cnt_d[idx]; }
  part[tid] = s; __syncthreads();
  for(int o=1;o<1024;o<<=1){
    int v = (tid >= o) ? part[tid-o] : 0;
    __syncthreads();
    part[tid] += v;
    __syncthreads();
  }
  int run = (tid == 0) ? 0 : part[tid-1];
  for(int j=0;j<per;j++){
    int idx = tid*per + j;
    if(idx < M){ off_d[idx] = run; run += cnt_d[idx]; }
  }
  if(tid == 1023) off_d[M] = run;
}

__global__ __launch_bounds__(256) void k_scatter(
    const int* __restrict__ etype, const int* __restrict__ src_idx,
    const int* __restrict__ dst_idx, const float* __restrict__ date,
    const int* __restrict__ ntype,
    const int* __restrict__ off_e, int* cur_e,
    const int* __restrict__ off_d, int* cur_d,
    const int* __restrict__ off_n, int* cur_n,
    int4* __restrict__ recs, int* dstlist, int* nperm, int* npos, int E, int M){
  __shared__ int lcnt[8], lbase[8], lnc[4], lnb[4];
  int tid = threadIdx.x;
  if(tid < 8) lcnt[tid] = 0;
  if(tid < 4) lnc[tid] = 0;
  __syncthreads();
  int g = blockIdx.x*256 + tid;
  int r = 0, lrank = 0, t = 0, nrank = 0;
  bool inE = (g < E), inM = (g < M);
  if(inE){ r = etype[g]; lrank = atomicAdd(&lcnt[r], 1); }
  if(inM){ t = ntype[g]; nrank = atomicAdd(&lnc[t], 1); }
  __syncthreads();
  if(tid < 8 && lcnt[tid]) lbase[tid] = atomicAdd(&cur_e[tid], lcnt[tid]);
  if(tid < 4 && lnc[tid])  lnb[tid]   = atomicAdd(&cur_n[tid], lnc[tid]);
  __syncthreads();
  if(inE){
    int p = off_e[r] + lbase[r] + lrank;
    int4 rec;
    rec.x = src_idx[g]; rec.y = dst_idx[g]; rec.z = g;
    rec.w = __float_as_int(date[g]);
    recs[p] = rec;
    int d = rec.y;
    int q = off_d[d] + atomicAdd(&cur_d[d], 1);   // ~10-way contention, benign
    dstlist[q] = p;                               // etype-sorted position
  }
  if(inM){
    int np = off_n[t] + lnb[t] + nrank;
    npos[g] = np;
    nperm[np] = g;
  }
}

// ---------------- weight convert+transpose: f32 [K][128] -> bf16 [128][K]
// 32x32 tiles via LDS; 512 blocks cover Wq(128) Wk(160) Wv(160) Wa(64)
__global__ __launch_bounds__(256) void k_convw(
    const float* __restrict__ Wq, const float* __restrict__ Wk,
    const float* __restrict__ Wv, const float* __restrict__ Wa,
    unsigned short* Wq_t, unsigned short* Wk_t,
    unsigned short* Wv_t, unsigned short* Wa_t)
{
  __shared__ float tile[32][33];
  int b = blockIdx.x;
  const float* src; unsigned short* dst; int K, rem;
  if(b < 128){       int r = b >> 4;          rem = b & 15;   src = Wq + r*16384; dst = Wq_t + r*16384; K = 128; }
  else if(b < 288){  int u = b-128; int r = u/20; rem = u - r*20; src = Wk + r*20480; dst = Wk_t + r*20480; K = 160; }
  else if(b < 448){  int u = b-288; int r = u/20; rem = u - r*20; src = Wv + r*20480; dst = Wv_t + r*20480; K = 160; }
  else {             int u = b-448; int r = u >> 4; rem = u & 15; src = Wa + r*16384; dst = Wa_t + r*16384; K = 128; }
  int nkt = K >> 5;
  int ki = rem % nkt, oj = rem / nkt;
  int tx = threadIdx.x & 31, ty = threadIdx.x >> 5;   // 32 x 8
  #pragma unroll
  for(int j=0;j<4;j++){
    int row = ty + j*8;                               // k within tile
    tile[row][tx] = src[(size_t)(ki*32+row)*128 + oj*32 + tx];
  }
  __syncthreads();
  #pragma unroll
  for(int j=0;j<4;j++){
    int a = ty + j*8;                                 // o within tile
    dst[(size_t)(oj*32+a)*K + ki*32 + tx] = f2bf(tile[tx][a]);
  }
}

// ---------------- prep: temporal encode + LN; one wave per (edge, s|d)
__global__ __launch_bounds__(256) void k_prep(
  const float* __restrict__ src_h, const float* __restrict__ src_tw, const float* __restrict__ src_tb,
  const float* __restrict__ edge_h, const int4* __restrict__ recs,
  const float* __restrict__ g_s, const float* __restrict__ b_s,
  const float* __restrict__ g_d, const float* __restrict__ b_d,
  unsigned short* __restrict__ dia_s, unsigned short* __restrict__ dia_d, int E)
{
  int p = blockIdx.x*4 + (threadIdx.x >> 6);
  bool isS = p < E;
  int pe = isS ? p : p - E;
  if(pe >= E) return;
  int lane = threadIdx.x & 63;
  int4 rec = recs[pe];
  float t = __int_as_float(rec.w);

  if(isS){ // dia_s: [sin(tw*t+tb)*h[:32], h[32:128], edge_h] -> LN(160)
    int s = rec.x, e = rec.z;
    float2 h2 = *(const float2*)(src_h + (size_t)s*128 + 2*lane);
    float x0 = h2.x, x1 = h2.y;
    if(lane < 16){
      float2 tw2 = *(const float2*)(src_tw + s*32 + 2*lane);
      float2 tb2 = *(const float2*)(src_tb + s*32 + 2*lane);
      x0 = __sinf(tw2.x*t + tb2.x) * h2.x;
      x1 = __sinf(tw2.y*t + tb2.y) * h2.y;
    }
    float e0 = 0.f, e1 = 0.f;
    if(lane >= 16 && lane < 32){
      float2 eh = *(const float2*)(edge_h + (size_t)e*32 + 2*(lane-16));
      e0 = eh.x; e1 = eh.y;
    }
    float s1 = x0+x1+e0+e1, s2 = x0*x0+x1*x1+e0*e0+e1*e1;
    #pragma unroll
    for(int i=1;i<64;i<<=1){ s1 += __shfl_xor(s1,i); s2 += __shfl_xor(s2,i); }
    float mu = s1*(1.f/160.f);
    float var = s2*(1.f/160.f) - mu*mu;
    float sc = rsqrtf(var + 1e-5f);
    float2 g2 = *(const float2*)(g_s + 2*lane);
    float2 b2 = *(const float2*)(b_s + 2*lane);
    float o0 = (x0-mu)*sc*g2.x + b2.x;
    float o1 = (x1-mu)*sc*g2.y + b2.y;
    ((unsigned*)dia_s)[(size_t)pe*80 + lane] = (unsigned)f2bf(o0) | ((unsigned)f2bf(o1)<<16);
    if(lane >= 16 && lane < 32){
      float2 g2e = *(const float2*)(g_s + 128 + 2*(lane-16));
      float2 b2e = *(const float2*)(b_s + 128 + 2*(lane-16));
      float q0 = (e0-mu)*sc*g2e.x + b2e.x;
      float q1 = (e1-mu)*sc*g2e.y + b2e.y;
      ((unsigned*)dia_s)[(size_t)pe*80 + 48 + lane] = (unsigned)f2bf(q0) | ((unsigned)f2bf(q1)<<16);
    }
  } else { // dia_d: LN(128)
    int d = rec.y;
    float2 h2 = *(const float2*)(src_h + (size_t)d*128 + 2*lane);
    float y0 = h2.x, y1 = h2.y;
    if(lane < 16){
      float2 tw2 = *(const float2*)(src_tw + d*32 + 2*lane);
      float2 tb2 = *(const float2*)(src_tb + d*32 + 2*lane);
      y0 = __sinf(tw2.x*t + tb2.x) * h2.x;
      y1 = __sinf(tw2.y*t + tb2.y) * h2.y;
    }
    float s1 = y0+y1, s2 = y0*y0+y1*y1;
    #pragma unroll
    for(int i=1;i<64;i<<=1){ s1 += __shfl_xor(s1,i); s2 += __shfl_xor(s2,i); }
    float mu = s1*(1.f/128.f);
    float var = s2*(1.f/128.f) - mu*mu;
    float sc = rsqrtf(var + 1e-5f);
    float2 g2 = *(const float2*)(g_d + 2*lane);
    float2 b2 = *(const float2*)(b_d + 2*lane);
    float o0 = (y0-mu)*sc*g2.x + b2.x;
    float o1 = (y1-mu)*sc*g2.y + b2.y;
    ((unsigned*)dia_d)[(size_t)pe*64 + lane] = (unsigned)f2bf(o0) | ((unsigned)f2bf(o1)<<16);
  }
}

// ---------------- LDS staging: rows x (c16 int4-chunks of 8 shorts), 256 thr
// c16 MUST equal row_shorts/8 (16 for 128-wide, 20 for 160-wide rows).
__device__ __forceinline__ void stage(const unsigned short* __restrict__ src, int srcld,
                                      unsigned short* dst, int dstld,
                                      int rows, int c16, int tid, int nv){
  int total = rows * c16;
  for(int idx = tid; idx < total; idx += 256){
    int rr = idx / c16, c = idx - rr*c16;
    int4 v = make_int4(0,0,0,0);
    if(rr < nv) v = *(const int4*)(src + (size_t)rr*srcld + c*8);
    *(int4*)(dst + rr*dstld + c*8) = v;
  }
}

// ---------------- GEMM from LDS-resident A[64][lda] and W[128][ldw], no barriers
template<int KD>
__device__ __forceinline__ void gemm_lds(
  const unsigned short* A, int lda,
  const unsigned short* W, int ldw,
  f32x4* acc, int tid)
{
  int lane = tid & 63, w = tid >> 6, m = lane & 15, quad = lane >> 4;
  #pragma unroll
  for(int i=0;i<8;i++) acc[i] = (f32x4){0.f,0.f,0.f,0.f};
  #pragma unroll
  for(int k0=0; k0<KD; k0+=32){
    short8 b0 = *(const short8*)(W + (w*32 +      m)*ldw + k0 + quad*8);
    short8 b1 = *(const short8*)(W + (w*32 + 16 + m)*ldw + k0 + quad*8);
    #pragma unroll
    for(int rt=0; rt<4; rt++){
      short8 af = *(const short8*)(A + (rt*16 + m)*lda + k0 + quad*8);
      acc[rt*2+0] = __builtin_amdgcn_mfma_f32_16x16x32_bf16(af, b0, acc[rt*2+0], 0,0,0);
      acc[rt*2+1] = __builtin_amdgcn_mfma_f32_16x16x32_bf16(af, b1, acc[rt*2+1], 0,0,0);
    }
  }
}

// ---------------- fused typed q/k/v: persistent blocks, weights in LDS
// dyn LDS layout (shorts): Wq[128*136] Wk[128*168] Wv[128*168] Ad[64*136] As[64*168]
#define WQ_OFF 0
#define WK_OFF 17408
#define WV_OFF 38912
#define AD_OFF 60416
#define AS_OFF 69120
#define QKV_LDS_BYTES 159744

__global__ __launch_bounds__(256) void k_qkv(
  const unsigned short* __restrict__ dia_d, const unsigned short* __restrict__ dia_s,
  const unsigned short* __restrict__ Wq_t, const unsigned short* __restrict__ Wk_t,
  const unsigned short* __restrict__ Wv_t,
  const int* __restrict__ cnt_e, const int* __restrict__ off_e,
  float* __restrict__ abuf, unsigned short* __restrict__ vbuf)
{
  extern __shared__ __align__(16) unsigned short sm[];
  unsigned short* Wq_l = sm + WQ_OFF;
  unsigned short* Wk_l = sm + WK_OFF;
  unsigned short* Wv_l = sm + WV_OFF;
  unsigned short* Ad   = sm + AD_OFF;
  unsigned short* As   = sm + AS_OFF;

  int tid = threadIdx.x;
  int lane = tid & 63, w = tid >> 6, m = lane & 15, quad = lane >> 4;
  // tile table over etypes
  int tbase[9]; int T = 0;
  #pragma unroll
  for(int i=0;i<8;i++){ tbase[i] = T; T += (cnt_e[i] + 63) >> 6; }
  tbase[8] = T;
  int NB = gridDim.x;
  int t0 = (int)(((long long)blockIdx.x * T) / NB);
  int t1 = (int)(((long long)(blockIdx.x+1) * T) / NB);
  int cur_r = -1;
  const float inv = 0.08838834764831845f;

  for(int t = t0; t < t1; t++){
    int r = 0;
    #pragma unroll
    for(int i=1;i<8;i++) if(t >= tbase[i]) r = i;
    int tl = t - tbase[r];
    int row0 = off_e[r] + tl*64;
    int nv = min(64, cnt_e[r] - tl*64);

    __syncthreads();                        // prior tile's LDS reads done
    if(r != cur_r){
      stage(Wq_t + r*16384, 128, Wq_l, 136, 128, 16, tid, 128);
      stage(Wk_t + r*20480, 160, Wk_l, 168, 128, 20, tid, 128);
      stage(Wv_t + r*20480, 160, Wv_l, 168, 128, 20, tid, 128);
      cur_r = r;
    }
    stage(dia_d + (size_t)row0*128, 128, Ad, 136, 64, 16, tid, nv);
    stage(dia_s + (size_t)row0*160, 160, As, 168, 64, 20, tid, nv);
    __syncthreads();

    f32x4 qa[8], ka[8];
    gemm_lds<128>(Ad, 136, Wq_l, 136, qa, tid);
    gemm_lds<160>(As, 168, Wk_l, 168, ka, tid);
    #pragma unroll
    for(int rt=0; rt<4; rt++)
    #pragma unroll
    for(int ct=0; ct<2; ct++){
      #pragma unroll
      for(int reg=0; reg<4; reg++){
        float s = qa[rt*2+ct][reg] * ka[rt*2+ct][reg];
        s += __shfl_xor(s,1); s += __shfl_xor(s,2); s += __shfl_xor(s,4); s += __shfl_xor(s,8);
        int row = rt*16 + quad*4 + reg;
        if(m == 0 && row < nv) abuf[(size_t)(row0+row)*8 + w*2 + ct] = __expf(s * inv);
      }
    }
    gemm_lds<160>(As, 168, Wv_l, 168, qa, tid);   // reuse qa for v
    #pragma unroll
    for(int rt=0; rt<4; rt++)
    #pragma unroll
    for(int ct=0; ct<2; ct++)
    #pragma unroll
    for(int reg=0; reg<4; reg++){
      int row = rt*16 + quad*4 + reg;
      if(row < nv)
        vbuf[(size_t)(row0+row)*128 + w*32 + ct*16 + m] = f2bf(qa[rt*2+ct][reg]);
    }
  }
}

// ---------------- per-dst softmax + weighted aggregate; 1 wave per dst
__global__ __launch_bounds__(64) void k_aggr(
  const float* __restrict__ abuf, const unsigned short* __restrict__ vbuf,
  const int* __restrict__ dstlist, const int* __restrict__ off_d,
  const int* __restrict__ npos, const int* __restrict__ ntype,
  const float* __restrict__ h_bias, unsigned short* __restrict__ hpre)
{
  int d = blockIdx.x, lane = threadIdx.x;
  int o0 = off_d[d], cnt = off_d[d+1] - o0;
  int h = lane >> 3;
  float denp = 0.f;
  for(int i = (lane>>3); i < cnt; i += 8)
    denp += abuf[(size_t)dstlist[o0+i]*8 + (lane & 7)];
  denp += __shfl_xor(denp, 8); denp += __shfl_xor(denp, 16); denp += __shfl_xor(denp, 32);
  float dh = __shfl(denp, h);
  float rd = (dh > 0.f) ? (1.f/dh) : 0.f;
  float a0 = 0.f, a1 = 0.f;
  const unsigned* vb = (const unsigned*)vbuf;
  int i = 0;
  for(; i + 4 <= cnt; i += 4){
    int p0 = dstlist[o0+i], p1 = dstlist[o0+i+1], p2 = dstlist[o0+i+2], p3 = dstlist[o0+i+3];
    float l0 = abuf[(size_t)p0*8 + h], l1 = abuf[(size_t)p1*8 + h];
    float l2 = abuf[(size_t)p2*8 + h], l3 = abuf[(size_t)p3*8 + h];
    unsigned v0 = vb[(size_t)p0*64 + lane], v1 = vb[(size_t)p1*64 + lane];
    unsigned v2 = vb[(size_t)p2*64 + lane], v3 = vb[(size_t)p3*64 + lane];
    a0 += l0*bf2f((unsigned short)(v0&0xffff)) + l1*bf2f((unsigned short)(v1&0xffff))
        + l2*bf2f((unsigned short)(v2&0xffff)) + l3*bf2f((unsigned short)(v3&0xffff));
    a1 += l0*bf2f((unsigned short)(v0>>16)) + l1*bf2f((unsigned short)(v1>>16))
        + l2*bf2f((unsigned short)(v2>>16)) + l3*bf2f((unsigned short)(v3>>16));
  }
  for(; i < cnt; i++){
    int p = dstlist[o0+i];
    float al = abuf[(size_t)p*8 + h];
    unsigned v2 = vb[(size_t)p*64 + lane];
    a0 += al * bf2f((unsigned short)(v2 & 0xffff));
    a1 += al * bf2f((unsigned short)(v2 >> 16));
  }
  a0 *= rd; a1 *= rd;
  int t = ntype[d];
  a0 += h_bias[t*128 + 2*lane];
  a1 += h_bias[t*128 + 2*lane + 1];
  ((unsigned*)hpre)[(size_t)npos[d]*64 + lane] =
      (unsigned)f2bf(a0) | ((unsigned)f2bf(a1) << 16);
}

// ---------------- final typed GEMM (Wa) + gate + residual (64-row tiles)
__global__ __launch_bounds__(256) void k_final(
  const unsigned short* __restrict__ hpre, const unsigned short* __restrict__ Wa_t,
  const int* __restrict__ cnt_n, const int* __restrict__ off_n, const int* __restrict__ nperm,
  const float* __restrict__ skip, const float* __restrict__ src_h, float* __restrict__ out)
{
  __shared__ __align__(16) unsigned short U[64*136];
  __shared__ __align__(16) unsigned short Wb[128*136];
  int bid = blockIdx.x;
  int r = -1, tl0 = 0, accT = 0;
  #pragma unroll
  for(int i=0;i<4;i++){
    int n = cnt_n[i], tt = (n + 63) >> 6;
    if(r < 0 && bid < accT + tt){ r = i; tl0 = bid - accT; }
    accT += tt;
  }
  if(r < 0) return;
  int row0 = off_n[r] + tl0*64;
  int nv = min(64, cnt_n[r] - tl0*64);
  float gate = 1.f / (1.f + __expf(-skip[r]));
  int tid = threadIdx.x;
  int lane = tid & 63, w = tid >> 6, m = lane & 15, quad = lane >> 4;
  stage(hpre + (size_t)row0*128, 128, U, 136, 64, 16, tid, nv);
  stage(Wa_t + r*16384, 128, Wb, 136, 128, 16, tid, 128);
  __syncthreads();
  f32x4 acc[8];
  gemm_lds<128>(U, 136, Wb, 136, acc, tid);
  #pragma unroll
  for(int rt=0; rt<4; rt++)
  #pragma unroll
  for(int ct=0; ct<2; ct++)
  #pragma unroll
  for(int reg=0; reg<4; reg++){
    int row = rt*16 + quad*4 + reg;
    if(row < nv){
      int dd = nperm[row0+row];
      int col = w*32 + ct*16 + m;
      out[(size_t)dd*128 + col] = acc[rt*2+ct][reg]*gate + src_h[(size_t)dd*128 + col]*(1.f - gate);
    }
  }
}

// ---------------------------------------------------------------------------
extern "C" void kernel_launch(void* const* d_in, const int* in_sizes, int n_in,
                              void* d_out, int out_size, void* d_ws, size_t ws_size,
                              hipStream_t stream)
{
  const float* src_h  = (const float*)d_in[0];
  const float* src_tw = (const float*)d_in[1];
  const float* src_tb = (const float*)d_in[2];
  const float* edge_h = (const float*)d_in[3];
  const float* date   = (const float*)d_in[4];
  const int*   src_idx= (const int*)d_in[5];
  const int*   dst_idx= (const int*)d_in[6];
  const int*   etype  = (const int*)d_in[7];
  const int*   ntype  = (const int*)d_in[8];
  const float* Wq     = (const float*)d_in[9];
  const float* Wk     = (const float*)d_in[10];
  const float* Wv     = (const float*)d_in[11];
  const float* Wa     = (const float*)d_in[12];
  const float* h_bias = (const float*)d_in[13];
  const float* skip   = (const float*)d_in[14];
  const float* g_s    = (const float*)d_in[15];
  const float* b_s    = (const float*)d_in[16];
  const float* g_d    = (const float*)d_in[17];
  const float* b_d    = (const float*)d_in[18];
  float* out = (float*)d_out;

  const int E = in_sizes[4];   // date
  const int M = in_sizes[8];   // ntype

  char* base = (char*)d_ws;
  size_t off = 0;
  auto alloc = [&](size_t bytes)->char*{
    off = (off + 255) & ~(size_t)255;
    char* p = base + off; off += bytes; return p;
  };
  int* cnt_e = (int*)alloc((size_t)(24 + 2*M)*4);
  int* cur_e = cnt_e + 8;
  int* cnt_n = cur_e + 8;
  int* cur_n = cnt_n + 4;
  int* cnt_d = cur_n + 4;
  int* cur_d = cnt_d + M;
  const int nzero = 24 + 2*M;
  int* off_e = (int*)alloc(9*4);
  int* off_n = (int*)alloc(5*4);
  int* off_d = (int*)alloc((size_t)(M+1)*4);
  int4* recs   = (int4*)alloc((size_t)E*16);
  int* dstlist = (int*)alloc((size_t)E*4);
  int* nperm   = (int*)alloc((size_t)M*4);
  int* npos    = (int*)alloc((size_t)M*4);
  unsigned short* Wq_t = (unsigned short*)alloc((size_t)8*128*128*2);
  unsigned short* Wk_t = (unsigned short*)alloc((size_t)8*160*128*2);
  unsigned short* Wv_t = (unsigned short*)alloc((size_t)8*160*128*2);
  unsigned short* Wa_t = (unsigned short*)alloc((size_t)4*128*128*2);
  unsigned short* dia_d = (unsigned short*)alloc((size_t)E*128*2);
  unsigned short* dia_s = (unsigned short*)alloc((size_t)E*160*2);
  unsigned short* vbuf  = (unsigned short*)alloc((size_t)E*128*2);
  unsigned short* hpre  = (unsigned short*)alloc((size_t)M*128*2);
  float* abuf = (float*)alloc((size_t)E*8*4);

  static bool attr_set = false;
  if(!attr_set){
    (void)hipFuncSetAttribute((const void*)k_qkv,
        hipFuncAttributeMaxDynamicSharedMemorySize, QKV_LDS_BYTES);
    attr_set = true;
  }

  k_zero<<<dim3((nzero+255)/256), dim3(256), 0, stream>>>(cnt_e, nzero);
  k_hist<<<dim3((E+255)/256), dim3(256), 0, stream>>>(etype, dst_idx, ntype, cnt_e, cnt_d, cnt_n, E, M);
  k_scan<<<dim3(1), dim3(1024), 0, stream>>>(cnt_e, off_e, cnt_n, off_n, cnt_d, off_d, M);
  k_scatter<<<dim3((E+255)/256), dim3(256), 0, stream>>>(etype, src_idx, dst_idx, date, ntype,
      off_e, cur_e, off_d, cur_d, off_n, cur_n, recs, dstlist, nperm, npos, E, M);
  k_convw<<<dim3(512), dim3(256), 0, stream>>>(Wq, Wk, Wv, Wa, Wq_t, Wk_t, Wv_t, Wa_t);
  k_prep<<<dim3((2*E+3)/4), dim3(256), 0, stream>>>(src_h, src_tw, src_tb, edge_h, recs,
      g_s, b_s, g_d, b_d, dia_s, dia_d, E);
  k_qkv<<<dim3(256), dim3(256), QKV_LDS_BYTES, stream>>>(dia_d, dia_s, Wq_t, Wk_t, Wv_t,
      cnt_e, off_e, abuf, vbuf);
  k_aggr<<<dim3(M), dim3(64), 0, stream>>>(abuf, vbuf, dstlist, off_d, npos, ntype, h_bias, hpre);
  k_final<<<dim3(M/64 + 5), dim3(256), 0, stream>>>(hpre, Wa_t, cnt_n, off_n, nperm, skip, src_h, out);
}

// Round 8
// 295.564 us; speedup vs baseline: 1.0761x; 1.0761x over previous
//
#include <hip/hip_runtime.h>

// ---------------------------------------------------------------------------
// HTGT layer: sort-by-type + bf16 MFMA pipeline
// R8: k_qkv = R2's proven chunked-Bt gemm64 structure (58us) with Ad/As
//     UNIONED into one buffer: LDS 49152 -> 31744 B -> 5 blocks/CU (20
//     waves/CU) vs R7's 1 block/CU (83us, Mfma 5%). Lesson: weights live in
//     L2; occupancy/TLP beats weight-amortization (R7) and zero-barrier
//     K-loops at 2 blocks/CU (R6). launch_bounds(256,5) pins VGPR<=102.
// ---------------------------------------------------------------------------

typedef __attribute__((ext_vector_type(8))) short short8;
typedef __attribute__((ext_vector_type(4))) float f32x4;

__device__ __forceinline__ unsigned short f2bf(float f){
  union { float f; unsigned u; } x; x.f = f;
  unsigned r = x.u + 0x7FFFu + ((x.u >> 16) & 1u);
  return (unsigned short)(r >> 16);
}
__device__ __forceinline__ float bf2f(unsigned short b){
  union { unsigned u; float f; } x; x.u = ((unsigned)b) << 16;
  return x.f;
}

// ---------------- setup kernels ----------------

__global__ void k_zero(int* __restrict__ p, int n){
  int i = blockIdx.x*256 + threadIdx.x;
  if(i < n) p[i] = 0;
}

__global__ __launch_bounds__(256) void k_hist(
    const int* __restrict__ etype, const int* __restrict__ dst_idx,
    const int* __restrict__ ntype,
    int* cnt_e, int* cnt_d, int* cnt_n, int E, int M){
  __shared__ int le[8], ln[4];
  int tid = threadIdx.x;
  if(tid < 8) le[tid] = 0;
  if(tid < 4) ln[tid] = 0;
  __syncthreads();
  int g = blockIdx.x*256 + tid;
  if(g < E){ atomicAdd(&le[etype[g]], 1); atomicAdd(&cnt_d[dst_idx[g]], 1); }
  if(g < M){ atomicAdd(&ln[ntype[g]], 1); }
  __syncthreads();
  if(tid < 8 && le[tid]) atomicAdd(&cnt_e[tid], le[tid]);
  if(tid < 4 && ln[tid]) atomicAdd(&cnt_n[tid], ln[tid]);
}

__global__ __launch_bounds__(1024) void k_scan(const int* __restrict__ cnt_e, int* off_e,
                                               const int* __restrict__ cnt_n, int* off_n,
                                               const int* __restrict__ cnt_d, int* off_d, int M){
  __shared__ int part[1024];
  int tid = threadIdx.x;
  if(tid == 0){
    int s = 0;
    for(int i=0;i<8;i++){ off_e[i]=s; s+=cnt_e[i]; } off_e[8]=s;
    s = 0;
    for(int i=0;i<4;i++){ off_n[i]=s; s+=cnt_n[i]; } off_n[4]=s;
  }
  int per = (M + 1023) >> 10;
  int s = 0;
  for(int j=0;j<per;j++){ int idx = tid*per + j; if(idx < M) s += cnt_d[idx]; }
  part[tid] = s; __syncthreads();
  for(int o=1;o<1024;o<<=1){
    int v = (tid >= o) ? part[tid-o] : 0;
    __syncthreads();
    part[tid] += v;
    __syncthreads();
  }
  int run = (tid == 0) ? 0 : part[tid-1];
  for(int j=0;j<per;j++){
    int idx = tid*per + j;
    if(idx < M){ off_d[idx] = run; run += cnt_d[idx]; }
  }
  if(tid == 1023) off_d[M] = run;
}

__global__ __launch_bounds__(256) void k_scatter(
    const int* __restrict__ etype, const int* __restrict__ src_idx,
    const int* __restrict__ dst_idx, const float* __restrict__ date,
    const int* __restrict__ ntype,
    const int* __restrict__ off_e, int* cur_e,
    const int* __restrict__ off_d, int* cur_d,
    const int* __restrict__ off_n, int* cur_n,
    int4* __restrict__ recs, int* dstlist, int* nperm, int* npos, int E, int M){
  __shared__ int lcnt[8], lbase[8], lnc[4], lnb[4];
  int tid = threadIdx.x;
  if(tid < 8) lcnt[tid] = 0;
  if(tid < 4) lnc[tid] = 0;
  __syncthreads();
  int g = blockIdx.x*256 + tid;
  int r = 0, lrank = 0, t = 0, nrank = 0;
  bool inE = (g < E), inM = (g < M);
  if(inE){ r = etype[g]; lrank = atomicAdd(&lcnt[r], 1); }
  if(inM){ t = ntype[g]; nrank = atomicAdd(&lnc[t], 1); }
  __syncthreads();
  if(tid < 8 && lcnt[tid]) lbase[tid] = atomicAdd(&cur_e[tid], lcnt[tid]);
  if(tid < 4 && lnc[tid])  lnb[tid]   = atomicAdd(&cur_n[tid], lnc[tid]);
  __syncthreads();
  if(inE){
    int p = off_e[r] + lbase[r] + lrank;
    int4 rec;
    rec.x = src_idx[g]; rec.y = dst_idx[g]; rec.z = g;
    rec.w = __float_as_int(date[g]);
    recs[p] = rec;
    int d = rec.y;
    int q = off_d[d] + atomicAdd(&cur_d[d], 1);   // ~10-way contention, benign
    dstlist[q] = p;                               // etype-sorted position
  }
  if(inM){
    int np = off_n[t] + lnb[t] + nrank;
    npos[g] = np;
    nperm[np] = g;
  }
}

// ---------------- weight convert+transpose: f32 [K][128] -> bf16 [128][K]
__global__ __launch_bounds__(256) void k_convw(
    const float* __restrict__ Wq, const float* __restrict__ Wk,
    const float* __restrict__ Wv, const float* __restrict__ Wa,
    unsigned short* Wq_t, unsigned short* Wk_t,
    unsigned short* Wv_t, unsigned short* Wa_t)
{
  __shared__ float tile[32][33];
  int b = blockIdx.x;
  const float* src; unsigned short* dst; int K, rem;
  if(b < 128){       int r = b >> 4;          rem = b & 15;   src = Wq + r*16384; dst = Wq_t + r*16384; K = 128; }
  else if(b < 288){  int u = b-128; int r = u/20; rem = u - r*20; src = Wk + r*20480; dst = Wk_t + r*20480; K = 160; }
  else if(b < 448){  int u = b-288; int r = u/20; rem = u - r*20; src = Wv + r*20480; dst = Wv_t + r*20480; K = 160; }
  else {             int u = b-448; int r = u >> 4; rem = u & 15; src = Wa + r*16384; dst = Wa_t + r*16384; K = 128; }
  int nkt = K >> 5;
  int ki = rem % nkt, oj = rem / nkt;
  int tx = threadIdx.x & 31, ty = threadIdx.x >> 5;   // 32 x 8
  #pragma unroll
  for(int j=0;j<4;j++){
    int row = ty + j*8;
    tile[row][tx] = src[(size_t)(ki*32+row)*128 + oj*32 + tx];
  }
  __syncthreads();
  #pragma unroll
  for(int j=0;j<4;j++){
    int a = ty + j*8;
    dst[(size_t)(oj*32+a)*K + ki*32 + tx] = f2bf(tile[tx][a]);
  }
}

// ---------------- prep: temporal encode + LN; one wave per (edge, s|d)
__global__ __launch_bounds__(256) void k_prep(
  const float* __restrict__ src_h, const float* __restrict__ src_tw, const float* __restrict__ src_tb,
  const float* __restrict__ edge_h, const int4* __restrict__ recs,
  const float* __restrict__ g_s, const float* __restrict__ b_s,
  const float* __restrict__ g_d, const float* __restrict__ b_d,
  unsigned short* __restrict__ dia_s, unsigned short* __restrict__ dia_d, int E)
{
  int p = blockIdx.x*4 + (threadIdx.x >> 6);
  bool isS = p < E;
  int pe = isS ? p : p - E;
  if(pe >= E) return;
  int lane = threadIdx.x & 63;
  int4 rec = recs[pe];
  float t = __int_as_float(rec.w);

  if(isS){ // dia_s: [sin(tw*t+tb)*h[:32], h[32:128], edge_h] -> LN(160)
    int s = rec.x, e = rec.z;
    float2 h2 = *(const float2*)(src_h + (size_t)s*128 + 2*lane);
    float x0 = h2.x, x1 = h2.y;
    if(lane < 16){
      float2 tw2 = *(const float2*)(src_tw + s*32 + 2*lane);
      float2 tb2 = *(const float2*)(src_tb + s*32 + 2*lane);
      x0 = __sinf(tw2.x*t + tb2.x) * h2.x;
      x1 = __sinf(tw2.y*t + tb2.y) * h2.y;
    }
    float e0 = 0.f, e1 = 0.f;
    if(lane >= 16 && lane < 32){
      float2 eh = *(const float2*)(edge_h + (size_t)e*32 + 2*(lane-16));
      e0 = eh.x; e1 = eh.y;
    }
    float s1 = x0+x1+e0+e1, s2 = x0*x0+x1*x1+e0*e0+e1*e1;
    #pragma unroll
    for(int i=1;i<64;i<<=1){ s1 += __shfl_xor(s1,i); s2 += __shfl_xor(s2,i); }
    float mu = s1*(1.f/160.f);
    float var = s2*(1.f/160.f) - mu*mu;
    float sc = rsqrtf(var + 1e-5f);
    float2 g2 = *(const float2*)(g_s + 2*lane);
    float2 b2 = *(const float2*)(b_s + 2*lane);
    float o0 = (x0-mu)*sc*g2.x + b2.x;
    float o1 = (x1-mu)*sc*g2.y + b2.y;
    ((unsigned*)dia_s)[(size_t)pe*80 + lane] = (unsigned)f2bf(o0) | ((unsigned)f2bf(o1)<<16);
    if(lane >= 16 && lane < 32){
      float2 g2e = *(const float2*)(g_s + 128 + 2*(lane-16));
      float2 b2e = *(const float2*)(b_s + 128 + 2*(lane-16));
      float q0 = (e0-mu)*sc*g2e.x + b2e.x;
      float q1 = (e1-mu)*sc*g2e.y + b2e.y;
      ((unsigned*)dia_s)[(size_t)pe*80 + 48 + lane] = (unsigned)f2bf(q0) | ((unsigned)f2bf(q1)<<16);
    }
  } else { // dia_d: LN(128)
    int d = rec.y;
    float2 h2 = *(const float2*)(src_h + (size_t)d*128 + 2*lane);
    float y0 = h2.x, y1 = h2.y;
    if(lane < 16){
      float2 tw2 = *(const float2*)(src_tw + d*32 + 2*lane);
      float2 tb2 = *(const float2*)(src_tb + d*32 + 2*lane);
      y0 = __sinf(tw2.x*t + tb2.x) * h2.x;
      y1 = __sinf(tw2.y*t + tb2.y) * h2.y;
    }
    float s1 = y0+y1, s2 = y0*y0+y1*y1;
    #pragma unroll
    for(int i=1;i<64;i<<=1){ s1 += __shfl_xor(s1,i); s2 += __shfl_xor(s2,i); }
    float mu = s1*(1.f/128.f);
    float var = s2*(1.f/128.f) - mu*mu;
    float sc = rsqrtf(var + 1e-5f);
    float2 g2 = *(const float2*)(g_d + 2*lane);
    float2 b2 = *(const float2*)(b_d + 2*lane);
    float o0 = (y0-mu)*sc*g2.x + b2.x;
    float o1 = (y1-mu)*sc*g2.y + b2.y;
    ((unsigned*)dia_d)[(size_t)pe*64 + lane] = (unsigned)f2bf(o0) | ((unsigned)f2bf(o1)<<16);
  }
}

// ---------------- LDS staging: rows x (c16 int4-chunks of 8 shorts), 256 thr
__device__ __forceinline__ void stage(const unsigned short* __restrict__ src, int srcld,
                                      unsigned short* dst, int dstld,
                                      int rows, int c16, int tid, int nv){
  int total = rows * c16;
  for(int idx = tid; idx < total; idx += 256){
    int rr = idx / c16, c = idx - rr*c16;
    int4 v = make_int4(0,0,0,0);
    if(rr < nv) v = *(const int4*)(src + (size_t)rr*srcld + c*8);
    *(int4*)(dst + rr*dstld + c*8) = v;
  }
}

// ---------------- chunked-Bt GEMM: A in LDS [64][lda], W global [128][Kd]
// stages 128x32 weight chunk into Bt per k-step (2 barriers/step)
__device__ __forceinline__ void gemm64(
  const unsigned short* A, int lda,
  const unsigned short* __restrict__ Wg, int Kd,
  unsigned short* Bt, f32x4* acc, int tid)
{
  int lane = tid & 63, w = tid >> 6, m = lane & 15, quad = lane >> 4;
  #pragma unroll
  for(int i=0;i<8;i++) acc[i] = (f32x4){0.f,0.f,0.f,0.f};
  for(int k0=0; k0<Kd; k0+=32){
    __syncthreads();                       // Bt reuse barrier
    #pragma unroll
    for(int j=0;j<2;j++){
      int idx = j*256 + tid;               // 0..511
      int n = idx >> 2, qc = idx & 3;      // weight row, 8-short quarter
      *(int4*)(Bt + n*40 + qc*8) = *(const int4*)(Wg + (size_t)n*Kd + k0 + qc*8);
    }
    __syncthreads();
    short8 b0 = *(const short8*)(Bt + (w*32 +      m)*40 + quad*8);
    short8 b1 = *(const short8*)(Bt + (w*32 + 16 + m)*40 + quad*8);
    #pragma unroll
    for(int rt=0; rt<4; rt++){
      short8 af = *(const short8*)(A + (rt*16 + m)*lda + k0 + quad*8);
      acc[rt*2+0] = __builtin_amdgcn_mfma_f32_16x16x32_bf16(af, b0, acc[rt*2+0], 0,0,0);
      acc[rt*2+1] = __builtin_amdgcn_mfma_f32_16x16x32_bf16(af, b1, acc[rt*2+1], 0,0,0);
    }
  }
}

// ---------------- fused typed q/k/v GEMM + attention scores (exp stored)
// LDS: U (union Ad/As, 21504 B) + Bt (10240 B) = 31744 B -> 5 blocks/CU
__global__ __launch_bounds__(256, 5) void k_qkv(
  const unsigned short* __restrict__ dia_d, const unsigned short* __restrict__ dia_s,
  const unsigned short* __restrict__ Wq_t, const unsigned short* __restrict__ Wk_t,
  const unsigned short* __restrict__ Wv_t,
  const int* __restrict__ cnt_e, const int* __restrict__ off_e,
  float* __restrict__ abuf, unsigned short* __restrict__ vbuf)
{
  __shared__ __align__(16) unsigned short U[64*168];
  __shared__ __align__(16) unsigned short Bt[128*40];
  int bid = blockIdx.x;
  int r = -1, tl0 = 0, accT = 0;
  #pragma unroll
  for(int i=0;i<8;i++){
    int n = cnt_e[i], tt = (n + 63) >> 6;
    if(r < 0 && bid < accT + tt){ r = i; tl0 = bid - accT; }
    accT += tt;
  }
  if(r < 0) return;
  int row0 = off_e[r] + tl0*64;
  int nv = min(64, cnt_e[r] - tl0*64);
  int tid = threadIdx.x;
  int lane = tid & 63, w = tid >> 6, m = lane & 15, quad = lane >> 4;

  f32x4 qa[8], ka[8];
  // phase 1: q = LN_d * Wq_r   (U = Ad)
  stage(dia_d + (size_t)row0*128, 128, U, 136, 64, 16, tid, nv);
  gemm64(U, 136, Wq_t + r*16384, 128, Bt, qa, tid);
  __syncthreads();                          // U reads done before overwrite
  // phase 2: k = LN_s * Wk_r   (U = As)
  stage(dia_s + (size_t)row0*160, 160, U, 168, 64, 20, tid, nv);
  gemm64(U, 168, Wk_t + r*20480, 160, Bt, ka, tid);

  // a[row][head] = (q.k)/sqrt(128); head = w*2+ct; store exp(a)
  const float inv = 0.08838834764831845f;
  #pragma unroll
  for(int rt=0; rt<4; rt++)
  #pragma unroll
  for(int ct=0; ct<2; ct++){
    #pragma unroll
    for(int reg=0; reg<4; reg++){
      float s = qa[rt*2+ct][reg] * ka[rt*2+ct][reg];
      s += __shfl_xor(s,1); s += __shfl_xor(s,2); s += __shfl_xor(s,4); s += __shfl_xor(s,8);
      int row = rt*16 + quad*4 + reg;
      if(m == 0 && row < nv) abuf[(size_t)(row0+row)*8 + w*2 + ct] = __expf(s * inv);
    }
  }
  // phase 3: v = LN_s * Wv_r   (As persists in U)
  gemm64(U, 168, Wv_t + r*20480, 160, Bt, qa, tid);   // reuse qa for v
  #pragma unroll
  for(int rt=0; rt<4; rt++)
  #pragma unroll
  for(int ct=0; ct<2; ct++)
  #pragma unroll
  for(int reg=0; reg<4; reg++){
    int row = rt*16 + quad*4 + reg;
    if(row < nv)
      vbuf[(size_t)(row0+row)*128 + w*32 + ct*16 + m] = f2bf(qa[rt*2+ct][reg]);
  }
}

// ---------------- per-dst softmax + weighted aggregate; 1 wave per dst
__global__ __launch_bounds__(64) void k_aggr(
  const float* __restrict__ abuf, const unsigned short* __restrict__ vbuf,
  const int* __restrict__ dstlist, const int* __restrict__ off_d,
  const int* __restrict__ npos, const int* __restrict__ ntype,
  const float* __restrict__ h_bias, unsigned short* __restrict__ hpre)
{
  int d = blockIdx.x, lane = threadIdx.x;
  int o0 = off_d[d], cnt = off_d[d+1] - o0;
  int h = lane >> 3;
  float denp = 0.f;
  for(int i = (lane>>3); i < cnt; i += 8)
    denp += abuf[(size_t)dstlist[o0+i]*8 + (lane & 7)];
  denp += __shfl_xor(denp, 8); denp += __shfl_xor(denp, 16); denp += __shfl_xor(denp, 32);
  float dh = __shfl(denp, h);
  float rd = (dh > 0.f) ? (1.f/dh) : 0.f;
  float a0 = 0.f, a1 = 0.f;
  const unsigned* vb = (const unsigned*)vbuf;
  int i = 0;
  for(; i + 4 <= cnt; i += 4){
    int p0 = dstlist[o0+i], p1 = dstlist[o0+i+1], p2 = dstlist[o0+i+2], p3 = dstlist[o0+i+3];
    float l0 = abuf[(size_t)p0*8 + h], l1 = abuf[(size_t)p1*8 + h];
    float l2 = abuf[(size_t)p2*8 + h], l3 = abuf[(size_t)p3*8 + h];
    unsigned v0 = vb[(size_t)p0*64 + lane], v1 = vb[(size_t)p1*64 + lane];
    unsigned v2 = vb[(size_t)p2*64 + lane], v3 = vb[(size_t)p3*64 + lane];
    a0 += l0*bf2f((unsigned short)(v0&0xffff)) + l1*bf2f((unsigned short)(v1&0xffff))
        + l2*bf2f((unsigned short)(v2&0xffff)) + l3*bf2f((unsigned short)(v3&0xffff));
    a1 += l0*bf2f((unsigned short)(v0>>16)) + l1*bf2f((unsigned short)(v1>>16))
        + l2*bf2f((unsigned short)(v2>>16)) + l3*bf2f((unsigned short)(v3>>16));
  }
  for(; i < cnt; i++){
    int p = dstlist[o0+i];
    float al = abuf[(size_t)p*8 + h];
    unsigned v2 = vb[(size_t)p*64 + lane];
    a0 += al * bf2f((unsigned short)(v2 & 0xffff));
    a1 += al * bf2f((unsigned short)(v2 >> 16));
  }
  a0 *= rd; a1 *= rd;
  int t = ntype[d];
  a0 += h_bias[t*128 + 2*lane];
  a1 += h_bias[t*128 + 2*lane + 1];
  ((unsigned*)hpre)[(size_t)npos[d]*64 + lane] =
      (unsigned)f2bf(a0) | ((unsigned)f2bf(a1) << 16);
}

// ---------------- final typed GEMM (Wa) + gate + residual (64-row tiles)
__global__ __launch_bounds__(256) void k_final(
  const unsigned short* __restrict__ hpre, const unsigned short* __restrict__ Wa_t,
  const int* __restrict__ cnt_n, const int* __restrict__ off_n, const int* __restrict__ nperm,
  const float* __restrict__ skip, const float* __restrict__ src_h, float* __restrict__ out)
{
  __shared__ __align__(16) unsigned short U[64*136];
  __shared__ __align__(16) unsigned short Bt[128*40];
  int bid = blockIdx.x;
  int r = -1, tl0 = 0, accT = 0;
  #pragma unroll
  for(int i=0;i<4;i++){
    int n = cnt_n[i], tt = (n + 63) >> 6;
    if(r < 0 && bid < accT + tt){ r = i; tl0 = bid - accT; }
    accT += tt;
  }
  if(r < 0) return;
  int row0 = off_n[r] + tl0*64;
  int nv = min(64, cnt_n[r] - tl0*64);
  float gate = 1.f / (1.f + __expf(-skip[r]));
  int tid = threadIdx.x;
  int lane = tid & 63, w = tid >> 6, m = lane & 15, quad = lane >> 4;
  stage(hpre + (size_t)row0*128, 128, U, 136, 64, 16, tid, nv);
  f32x4 acc[8];
  gemm64(U, 136, Wa_t + r*16384, 128, Bt, acc, tid);
  #pragma unroll
  for(int rt=0; rt<4; rt++)
  #pragma unroll
  for(int ct=0; ct<2; ct++)
  #pragma unroll
  for(int reg=0; reg<4; reg++){
    int row = rt*16 + quad*4 + reg;
    if(row < nv){
      int dd = nperm[row0+row];
      int col = w*32 + ct*16 + m;
      out[(size_t)dd*128 + col] = acc[rt*2+ct][reg]*gate + src_h[(size_t)dd*128 + col]*(1.f - gate);
    }
  }
}

// ---------------------------------------------------------------------------
extern "C" void kernel_launch(void* const* d_in, const int* in_sizes, int n_in,
                              void* d_out, int out_size, void* d_ws, size_t ws_size,
                              hipStream_t stream)
{
  const float* src_h  = (const float*)d_in[0];
  const float* src_tw = (const float*)d_in[1];
  const float* src_tb = (const float*)d_in[2];
  const float* edge_h = (const float*)d_in[3];
  const float* date   = (const float*)d_in[4];
  const int*   src_idx= (const int*)d_in[5];
  const int*   dst_idx= (const int*)d_in[6];
  const int*   etype  = (const int*)d_in[7];
  const int*   ntype  = (const int*)d_in[8];
  const float* Wq     = (const float*)d_in[9];
  const float* Wk     = (const float*)d_in[10];
  const float* Wv     = (const float*)d_in[11];
  const float* Wa     = (const float*)d_in[12];
  const float* h_bias = (const float*)d_in[13];
  const float* skip   = (const float*)d_in[14];
  const float* g_s    = (const float*)d_in[15];
  const float* b_s    = (const float*)d_in[16];
  const float* g_d    = (const float*)d_in[17];
  const float* b_d    = (const float*)d_in[18];
  float* out = (float*)d_out;

  const int E = in_sizes[4];   // date
  const int M = in_sizes[8];   // ntype

  char* base = (char*)d_ws;
  size_t off = 0;
  auto alloc = [&](size_t bytes)->char*{
    off = (off + 255) & ~(size_t)255;
    char* p = base + off; off += bytes; return p;
  };
  int* cnt_e = (int*)alloc((size_t)(24 + 2*M)*4);
  int* cur_e = cnt_e + 8;
  int* cnt_n = cur_e + 8;
  int* cur_n = cnt_n + 4;
  int* cnt_d = cur_n + 4;
  int* cur_d = cnt_d + M;
  const int nzero = 24 + 2*M;
  int* off_e = (int*)alloc(9*4);
  int* off_n = (int*)alloc(5*4);
  int* off_d = (int*)alloc((size_t)(M+1)*4);
  int4* recs   = (int4*)alloc((size_t)E*16);
  int* dstlist = (int*)alloc((size_t)E*4);
  int* nperm   = (int*)alloc((size_t)M*4);
  int* npos    = (int*)alloc((size_t)M*4);
  unsigned short* Wq_t = (unsigned short*)alloc((size_t)8*128*128*2);
  unsigned short* Wk_t = (unsigned short*)alloc((size_t)8*160*128*2);
  unsigned short* Wv_t = (unsigned short*)alloc((size_t)8*160*128*2);
  unsigned short* Wa_t = (unsigned short*)alloc((size_t)4*128*128*2);
  unsigned short* dia_d = (unsigned short*)alloc((size_t)E*128*2);
  unsigned short* dia_s = (unsigned short*)alloc((size_t)E*160*2);
  unsigned short* vbuf  = (unsigned short*)alloc((size_t)E*128*2);
  unsigned short* hpre  = (unsigned short*)alloc((size_t)M*128*2);
  float* abuf = (float*)alloc((size_t)E*8*4);

  k_zero<<<dim3((nzero+255)/256), dim3(256), 0, stream>>>(cnt_e, nzero);
  k_hist<<<dim3((E+255)/256), dim3(256), 0, stream>>>(etype, dst_idx, ntype, cnt_e, cnt_d, cnt_n, E, M);
  k_scan<<<dim3(1), dim3(1024), 0, stream>>>(cnt_e, off_e, cnt_n, off_n, cnt_d, off_d, M);
  k_scatter<<<dim3((E+255)/256), dim3(256), 0, stream>>>(etype, src_idx, dst_idx, date, ntype,
      off_e, cur_e, off_d, cur_d, off_n, cur_n, recs, dstlist, nperm, npos, E, M);
  k_convw<<<dim3(512), dim3(256), 0, stream>>>(Wq, Wk, Wv, Wa, Wq_t, Wk_t, Wv_t, Wa_t);
  k_prep<<<dim3((2*E+3)/4), dim3(256), 0, stream>>>(src_h, src_tw, src_tb, edge_h, recs,
      g_s, b_s, g_d, b_d, dia_s, dia_d, E);
  k_qkv<<<dim3(E/64 + 9), dim3(256), 0, stream>>>(dia_d, dia_s, Wq_t, Wk_t, Wv_t,
      cnt_e, off_e, abuf, vbuf);
  k_aggr<<<dim3(M), dim3(64), 0, stream>>>(abuf, vbuf, dstlist, off_d, npos, ntype, h_bias, hpre);
  k_final<<<dim3(M/64 + 5), dim3(256), 0, stream>>>(hpre, Wa_t, cnt_n, off_n, nperm, skip, src_h, out);
}